// Round 1
// baseline (520.144 us; speedup 1.0000x reference)
//
#include <hip/hip_runtime.h>
#include <hip/hip_bf16.h>
#include <stdint.h>

typedef __bf16 bf16_t;
typedef __bf16 bf16x8 __attribute__((ext_vector_type(8)));
typedef float f32x4 __attribute__((ext_vector_type(4)));

constexpr int BATCH = 8192;
constexpr int M = 2 * BATCH;          // both branches stacked: 16384 rows

// padded GEMM dims (K multiple of 64, N multiple of 128; zero-padded weights)
constexpr int K1 = 1216, N1 = 1664;   // [e|r] 1200 -> 1216 ; H 1600 -> 1664
constexpr int K2 = 1664, N2 = 1664;   // H -> H
constexpr int K3 = 1664, N3 = 896;    // H -> 2d (800 -> 896)
constexpr int K4 = 896,  N4 = 896;    // 2d -> 2d
constexpr int K5 = 896,  N5 = 512;    // 2d -> d (400 -> 512)

// ---------------------------------------------------------------- staging
__device__ __forceinline__ void gload_lds16(const void* g, void* l) {
  __builtin_amdgcn_global_load_lds(
      (const __attribute__((address_space(1))) void*)g,
      (__attribute__((address_space(3))) void*)l,
      16, 0, 0);
}

// ---------------------------------------------------------------- gather + reg + concat -> bf16 X [M, K1]
__global__ void gather_kernel(const int* __restrict__ a1, const int* __restrict__ r1,
                              const int* __restrict__ a2, const int* __restrict__ r2,
                              const float* __restrict__ ent, const float* __restrict__ rel,
                              bf16_t* __restrict__ X) {
  const int row = blockIdx.x;            // 0..M-1
  const int b   = row & (BATCH - 1);
  const int br  = row >> 13;             // 0: branch1, 1: branch2
  const int eidx = br ? a2[b] : a1[b];
  const int ridx = br ? r2[b] : r1[b];
  const float* __restrict__ esrc = ent + (size_t)eidx * 800;
  const float* __restrict__ rsrc = rel + (size_t)ridx * 400;
  bf16_t* __restrict__ dst = X + (size_t)row * K1;

  for (int g = threadIdx.x; g < K1 / 4; g += 256) {
    const int c = g * 4;
    float4 v = make_float4(0.f, 0.f, 0.f, 0.f);
    if (c < 800) {                       // entity part: _reg = clip(x+1, 0.05, 1e9)
      v = *(const float4*)(esrc + c);
      v.x = fminf(fmaxf(v.x + 1.f, 0.05f), 1e9f);
      v.y = fminf(fmaxf(v.y + 1.f, 0.05f), 1e9f);
      v.z = fminf(fmaxf(v.z + 1.f, 0.05f), 1e9f);
      v.w = fminf(fmaxf(v.w + 1.f, 0.05f), 1e9f);
    } else if (c < 1200) {               // relation part (no reg)
      v = *(const float4*)(rsrc + (c - 800));
    }                                    // else zero pad
    union { bf16_t h[4]; uint2 u; } pk;
    pk.h[0] = (bf16_t)v.x; pk.h[1] = (bf16_t)v.y;
    pk.h[2] = (bf16_t)v.z; pk.h[3] = (bf16_t)v.w;
    *(uint2*)(dst + c) = pk.u;
  }
}

// ---------------------------------------------------------------- weight f32 [Nr,Kc] -> bf16 [*,Kp] zero-padded
__global__ void convw_kernel(const float* __restrict__ src, bf16_t* __restrict__ dst,
                             int Nr, int Kc, int Kp, int total4) {
  const int idx = blockIdx.x * 256 + threadIdx.x;
  if (idx >= total4) return;
  const int kp4 = Kp >> 2;
  const int r = idx / kp4;
  const int c = (idx - r * kp4) << 2;
  union { bf16_t h[4]; uint2 u; } pk;
#pragma unroll
  for (int j = 0; j < 4; ++j) {
    const int cc = c + j;
    const float v = (r < Nr && cc < Kc) ? src[(size_t)r * Kc + cc] : 0.f;
    pk.h[j] = (bf16_t)v;
  }
  *(uint2*)(dst + (size_t)r * Kp + c) = pk.u;
}

// ---------------------------------------------------------------- GEMM: C[M,Nd] = act(A[M,Kd] * B[Nd,Kd]^T + bias)
// 128x128 tile, 4 waves (2x2), each wave 64x64 via 4x4 MFMA 16x16x32 frags, BK=64, global_load_lds staging.
enum { ACT_RELU = 0, ACT_REG = 1, ACT_NONE = 2 };

template <int ACT, int OUTMODE>   // OUTMODE: 0 = bf16, 1 = f32, 2 = both
__global__ __launch_bounds__(256)
void gemm_kernel(const bf16_t* __restrict__ A, const bf16_t* __restrict__ Bw,
                 const float* __restrict__ bias, int Nbias,
                 bf16_t* __restrict__ Cb, float* __restrict__ Cf,
                 int Kd, int Nd) {
  __shared__ __align__(16) bf16_t As[128 * 64];
  __shared__ __align__(16) bf16_t Bs[128 * 64];

  const int bn = blockIdx.x, bm = blockIdx.y;
  const int t = threadIdx.x;
  const int lane = t & 63;
  const int wv = t >> 6;
  const int wm = wv >> 1, wn = wv & 1;

  f32x4 acc[4][4];
#pragma unroll
  for (int i = 0; i < 4; ++i)
#pragma unroll
    for (int j = 0; j < 4; ++j) acc[i][j] = f32x4{0.f, 0.f, 0.f, 0.f};

  const size_t aBase = (size_t)(bm * 128) * Kd;
  const size_t bBase = (size_t)(bn * 128) * Kd;

  for (int kt = 0; kt < Kd; kt += 64) {
    __syncthreads();  // previous compute done before LDS overwrite
#pragma unroll
    for (int q = 0; q < 4; ++q) {
      const int lin = q * 256 + t;           // 0..1023 16B-chunks
      const int row = lin >> 3;              // 8 chunks per 64-elem row
      const int kc = (lin & 7) * 8;
      const int lofs = (q * 256 + wv * 64) * 16;  // wave-uniform LDS byte base
      gload_lds16(A + aBase + (size_t)row * Kd + kt + kc, (char*)As + lofs);
      gload_lds16(Bw + bBase + (size_t)row * Kd + kt + kc, (char*)Bs + lofs);
    }
    __syncthreads();  // vmcnt(0) drained by compiler before barrier

#pragma unroll
    for (int s = 0; s < 2; ++s) {
      const int k0 = s * 32 + ((lane >> 4) * 8);
      bf16x8 af[4], bf[4];
#pragma unroll
      for (int i = 0; i < 4; ++i) {
        const int ra = wm * 64 + i * 16 + (lane & 15);
        af[i] = *(const bf16x8*)(As + ra * 64 + k0);
        const int rb = wn * 64 + i * 16 + (lane & 15);
        bf[i] = *(const bf16x8*)(Bs + rb * 64 + k0);
      }
#pragma unroll
      for (int mi = 0; mi < 4; ++mi)
#pragma unroll
        for (int ni = 0; ni < 4; ++ni)
          acc[mi][ni] = __builtin_amdgcn_mfma_f32_16x16x32_bf16(af[mi], bf[ni], acc[mi][ni], 0, 0, 0);
    }
  }

  // epilogue: D frag layout col = lane&15, row = (lane>>4)*4 + j
  const int r0 = bm * 128 + wm * 64 + ((lane >> 4) * 4);
  const int c0 = bn * 128 + wn * 64 + (lane & 15);
#pragma unroll
  for (int ni = 0; ni < 4; ++ni) {
    const int col = c0 + ni * 16;
    const float bv = (col < Nbias) ? bias[col] : 0.f;
#pragma unroll
    for (int mi = 0; mi < 4; ++mi) {
#pragma unroll
      for (int j = 0; j < 4; ++j) {
        float v = acc[mi][ni][j] + bv;
        if (ACT == ACT_RELU) v = fmaxf(v, 0.f);
        else if (ACT == ACT_REG) v = fminf(fmaxf(v + 1.f, 0.05f), 1e9f);
        const size_t off = (size_t)(r0 + mi * 16 + j) * Nd + col;
        if (OUTMODE == 0 || OUTMODE == 2) Cb[off] = (bf16_t)v;
        if (OUTMODE == 1 || OUTMODE == 2) Cf[off] = v;
      }
    }
  }
}

// ---------------------------------------------------------------- softmax over K=2 + weighted combine
__global__ void combine_kernel(const float* __restrict__ L, const float* __restrict__ E,
                               float* __restrict__ out) {
  const int i = blockIdx.x * 256 + threadIdx.x;   // exact grid: BATCH*400
  const int b = i / 400;
  const int d = i - b * 400;
  const float l1 = L[(size_t)b * N5 + d];
  const float l2 = L[(size_t)(BATCH + b) * N5 + d];
  const float att1 = 1.f / (1.f + expf(l2 - l1));
  const float att2 = 1.f - att1;
  const float* E1 = E + (size_t)b * N3;
  const float* E2 = E + (size_t)(BATCH + b) * N3;
  out[i] = att1 * E1[d] + att2 * E2[d];                                  // alpha
  out[(size_t)BATCH * 400 + i] = att1 * E1[400 + d] + att2 * E2[400 + d]; // beta
}

// ----------------------------------------------------------------
extern "C" void kernel_launch(void* const* d_in, const int* in_sizes, int n_in,
                              void* d_out, int out_size, void* d_ws, size_t ws_size,
                              hipStream_t stream) {
  const int* a1 = (const int*)d_in[0];
  const int* r1 = (const int*)d_in[1];
  const int* a2 = (const int*)d_in[2];
  const int* r2 = (const int*)d_in[3];
  const float* ent = (const float*)d_in[4];
  const float* rel = (const float*)d_in[5];
  const float* pW1 = (const float*)d_in[6];
  const float* pb1 = (const float*)d_in[7];
  const float* pW2 = (const float*)d_in[8];
  const float* pb2 = (const float*)d_in[9];
  const float* pW0 = (const float*)d_in[10];
  const float* pb0 = (const float*)d_in[11];
  const float* iW1 = (const float*)d_in[12];
  const float* ib1 = (const float*)d_in[13];
  const float* iW2 = (const float*)d_in[14];
  const float* ib2 = (const float*)d_in[15];

  char* ws = (char*)d_ws;
  size_t o = 0;
  auto take = [&](size_t bytes) { char* p = ws + o; o += (bytes + 255) & ~(size_t)255; return p; };
  bf16_t* W1b  = (bf16_t*)take((size_t)N1 * K1 * 2);
  bf16_t* W2b  = (bf16_t*)take((size_t)N2 * K2 * 2);
  bf16_t* W0b  = (bf16_t*)take((size_t)N3 * K3 * 2);
  bf16_t* iW1b = (bf16_t*)take((size_t)N4 * K4 * 2);
  bf16_t* iW2b = (bf16_t*)take((size_t)N5 * K5 * 2);
  char* bufX = take((size_t)M * K1 * 2);  // X bf16 [M,K1]; later E bf16 [M,N3]
  char* bufY = take((size_t)M * N1 * 2);  // Y bf16 [M,N1]; later Hb bf16 [M,N4]
  char* bufZ = take((size_t)M * N2 * 2);  // Z bf16 [M,N2]; later L f32 [M,N5]
  float* Ef  = (float*)take((size_t)M * N3 * 4);  // E f32 for final combine

  bf16_t* Xb = (bf16_t*)bufX;
  bf16_t* Yb = (bf16_t*)bufY;
  bf16_t* Zb = (bf16_t*)bufZ;
  bf16_t* Eb = (bf16_t*)bufX;   // reuse: X dead after G1
  bf16_t* Hb = (bf16_t*)bufY;   // reuse: Y dead after G2
  float*  Lf = (float*)bufZ;    // reuse: Z dead after G3

  // weight conversions (zero-padded)
  auto cgrid = [](int n4) { return dim3((n4 + 255) / 256); };
  convw_kernel<<<cgrid(N1 * K1 / 4), 256, 0, stream>>>(pW1, W1b, 1600, 1200, K1, N1 * K1 / 4);
  convw_kernel<<<cgrid(N2 * K2 / 4), 256, 0, stream>>>(pW2, W2b, 1600, 1600, K2, N2 * K2 / 4);
  convw_kernel<<<cgrid(N3 * K3 / 4), 256, 0, stream>>>(pW0, W0b, 800, 1600, K3, N3 * K3 / 4);
  convw_kernel<<<cgrid(N4 * K4 / 4), 256, 0, stream>>>(iW1, iW1b, 800, 800, K4, N4 * K4 / 4);
  convw_kernel<<<cgrid(N5 * K5 / 4), 256, 0, stream>>>(iW2, iW2b, 400, 800, K5, N5 * K5 / 4);

  // gather + regularize + concat
  gather_kernel<<<M, 256, 0, stream>>>(a1, r1, a2, r2, ent, rel, Xb);

  // G1: Y = relu(X W1^T + b1)
  gemm_kernel<ACT_RELU, 0><<<dim3(N1 / 128, M / 128), 256, 0, stream>>>(Xb, W1b, pb1, 1600, Yb, nullptr, K1, N1);
  // G2: Z = relu(Y W2^T + b2)
  gemm_kernel<ACT_RELU, 0><<<dim3(N2 / 128, M / 128), 256, 0, stream>>>(Yb, W2b, pb2, 1600, Zb, nullptr, K2, N2);
  // G3: E = reg(Z W0^T + b0)  -> both bf16 (GEMM4 input) and f32 (combine input)
  gemm_kernel<ACT_REG, 2><<<dim3(N3 / 128, M / 128), 256, 0, stream>>>(Zb, W0b, pb0, 800, Eb, Ef, K3, N3);
  // G4: H = relu(E iW1^T + ib1)
  gemm_kernel<ACT_RELU, 0><<<dim3(N4 / 128, M / 128), 256, 0, stream>>>(Eb, iW1b, ib1, 800, Hb, nullptr, K4, N4);
  // G5: L = H iW2^T + ib2 (f32 logits)
  gemm_kernel<ACT_NONE, 1><<<dim3(N5 / 128, M / 128), 256, 0, stream>>>(Hb, iW2b, ib2, 400, nullptr, Lf, K5, N5);

  // softmax over the 2 branches + weighted sums
  combine_kernel<<<(BATCH * 400) / 256, 256, 0, stream>>>(Lf, Ef, (float*)d_out);
}

// Round 2
// 418.662 us; speedup vs baseline: 1.2424x; 1.2424x over previous
//
#include <hip/hip_runtime.h>
#include <hip/hip_bf16.h>
#include <stdint.h>

typedef __bf16 bf16_t;
typedef __bf16 bf16x8 __attribute__((ext_vector_type(8)));
typedef float f32x4 __attribute__((ext_vector_type(4)));

constexpr int BATCH = 8192;
constexpr int M = 2 * BATCH;          // both branches stacked: 16384 rows

// GEMM dims: compute-N padded to 256, store width = next K (multiple of 64)
constexpr int K1 = 1216;                    // [e|r] 1200 -> 1216
constexpr int N1c = 1792, N1s = 1664;       // H 1600: compute 1792, store 1664
constexpr int K2 = 1664;
constexpr int N2c = 1792, N2s = 1664;
constexpr int K3 = 1664;
constexpr int N3c = 1024, N3s = 1024;       // 2d 800 -> 1024
constexpr int K4 = 1024;
constexpr int N4c = 1024, N4s = 1024;
constexpr int K5 = 1024, N5 = 512;          // d 400 -> 512

// ---------------------------------------------------------------- staging
__device__ __forceinline__ void gload_lds16(const void* g, void* l) {
  __builtin_amdgcn_global_load_lds(
      (const __attribute__((address_space(1))) void*)g,
      (__attribute__((address_space(3))) void*)l,
      16, 0, 0);
}

#define CFENCE() asm volatile("" ::: "memory")
#define BAR()  { CFENCE(); __builtin_amdgcn_s_barrier(); CFENCE(); }

// ---------------------------------------------------------------- gather + reg + concat -> bf16 X [M, K1]
__global__ void gather_kernel(const int* __restrict__ a1, const int* __restrict__ r1,
                              const int* __restrict__ a2, const int* __restrict__ r2,
                              const float* __restrict__ ent, const float* __restrict__ rel,
                              bf16_t* __restrict__ X) {
  const int row = blockIdx.x;            // 0..M-1
  const int b   = row & (BATCH - 1);
  const int br  = row >> 13;             // 0: branch1, 1: branch2
  const int eidx = br ? a2[b] : a1[b];
  const int ridx = br ? r2[b] : r1[b];
  const float* __restrict__ esrc = ent + (size_t)eidx * 800;
  const float* __restrict__ rsrc = rel + (size_t)ridx * 400;
  bf16_t* __restrict__ dst = X + (size_t)row * K1;

  for (int g = threadIdx.x; g < K1 / 4; g += 256) {
    const int c = g * 4;
    float4 v = make_float4(0.f, 0.f, 0.f, 0.f);
    if (c < 800) {                       // entity part: _reg = clip(x+1, 0.05, 1e9)
      v = *(const float4*)(esrc + c);
      v.x = fminf(fmaxf(v.x + 1.f, 0.05f), 1e9f);
      v.y = fminf(fmaxf(v.y + 1.f, 0.05f), 1e9f);
      v.z = fminf(fmaxf(v.z + 1.f, 0.05f), 1e9f);
      v.w = fminf(fmaxf(v.w + 1.f, 0.05f), 1e9f);
    } else if (c < 1200) {               // relation part (no reg)
      v = *(const float4*)(rsrc + (c - 800));
    }                                    // else zero pad
    union { bf16_t h[4]; uint2 u; } pk;
    pk.h[0] = (bf16_t)v.x; pk.h[1] = (bf16_t)v.y;
    pk.h[2] = (bf16_t)v.z; pk.h[3] = (bf16_t)v.w;
    *(uint2*)(dst + c) = pk.u;
  }
}

// ---------------------------------------------------------------- weight f32 [Nr,Kc] -> bf16 [Np,Kp] zero-padded
__global__ void convw_kernel(const float* __restrict__ src, bf16_t* __restrict__ dst,
                             int Nr, int Kc, int Kp, int total4) {
  const int idx = blockIdx.x * 256 + threadIdx.x;
  if (idx >= total4) return;
  const int kp4 = Kp >> 2;
  const int r = idx / kp4;
  const int c = (idx - r * kp4) << 2;
  union { bf16_t h[4]; uint2 u; } pk;
#pragma unroll
  for (int j = 0; j < 4; ++j) {
    const int cc = c + j;
    const float v = (r < Nr && cc < Kc) ? src[(size_t)r * Kc + cc] : 0.f;
    pk.h[j] = (bf16_t)v;
  }
  *(uint2*)(dst + (size_t)r * Kp + c) = pk.u;
}

enum { ACT_RELU = 0, ACT_REG = 1, ACT_NONE = 2 };

// ---------------------------------------------------------------- 256x256 8-phase pipelined GEMM
// C[M,*] = act(A[M,Kd] * B[Nc,Kd]^T + bias); 512 thr = 8 waves (2m x 4n), BK=64.
// LDS: 8 slots of [256 rows][32 k] bf16 (16 KiB) = 128 KiB: slot(db, mat, khalf) = db*4 + mat*2 + kh.
// Per K-tile: 4 phases (khalf s, mhalf mh). Stage 1 slot/phase, 4-6 phases ahead of use.
// Gates: vmcnt(8) at end of ph2 and ph4 (counted, never 0 mid-loop); raw s_barrier only.
template <int ACT, int OUTMODE>   // OUTMODE: 0 = bf16, 1 = f32, 2 = both
__global__ __launch_bounds__(512)
void gemm256(const bf16_t* __restrict__ A, const bf16_t* __restrict__ Bw,
             const float* __restrict__ bias, int Nbias,
             bf16_t* __restrict__ Cb, float* __restrict__ Cf,
             int Kd, int Nstore, int NT, int gridN) {
  __shared__ __align__(16) bf16_t lds[8][8192];

  const int nwg = gridDim.x;
  const int id = blockIdx.x;
  const int swz = (id & 7) * (nwg >> 3) + (id >> 3);   // XCD-aware (nwg % 8 == 0)
  const int bn = swz % gridN, bm = swz / gridN;

  const int t = threadIdx.x;
  const int lane = t & 63;
  const int wv = t >> 6;
  const int wm = wv >> 2, wn = wv & 3;
  const int l15 = lane & 15;
  const int kbs = ((lane >> 4) << 4) ^ ((lane & 3) << 4);  // swizzled within-row byte off

  // staging per-thread constants: chunk c = q*512+t -> row q*128 + (t>>2), kchunk (t&3)^((t>>2)&3)
  const int srow = t >> 2;
  const int skc  = (t & 3) ^ (srow & 3);
  const bf16_t* aR0 = A  + (size_t)(bm * 256 + srow) * Kd + skc * 8;
  const bf16_t* aR1 = aR0 + (size_t)128 * Kd;
  const bf16_t* bR0 = Bw + (size_t)(bn * 256 + srow) * Kd + skc * 8;
  const bf16_t* bR1 = bR0 + (size_t)128 * Kd;
  const int ldsb0 = (wv * 64) * 16;
  const int ldsb1 = (512 + wv * 64) * 16;

  auto STAGE = [&](const bf16_t* r0p, const bf16_t* r1p, int kOff, bf16_t* slot) {
    gload_lds16(r0p + kOff, (char*)slot + ldsb0);
    gload_lds16(r1p + kOff, (char*)slot + ldsb1);
  };

  f32x4 acc[8][4];
#pragma unroll
  for (int i = 0; i < 8; ++i)
#pragma unroll
    for (int j = 0; j < 4; ++j) acc[i][j] = f32x4{0.f, 0.f, 0.f, 0.f};

  // prologue: tile0 (4 slots) + tile1 k-half0 (2 slots)
  STAGE(aR0, aR1, 0, lds[0]);
  STAGE(bR0, bR1, 0, lds[2]);
  STAGE(aR0, aR1, 32, lds[1]);
  STAGE(bR0, bR1, 32, lds[3]);
  if (NT > 1) {
    STAGE(aR0, aR1, 64, lds[4]);
    STAGE(bR0, bR1, 64, lds[6]);
    asm volatile("s_waitcnt vmcnt(8)" ::: "memory");   // A0(0),B0(0) landed
  } else {
    asm volatile("s_waitcnt vmcnt(4)" ::: "memory");
  }
  __builtin_amdgcn_s_barrier();
  CFENCE();

  bf16x8 bfr[4];
  int db = 0;
  for (int kt = 0; kt < NT; ++kt, db ^= 1) {
    const bool p1 = (kt + 1) < NT;
    const bool p2 = (kt + 2) < NT;
    bf16_t* const cur = (bf16_t*)lds[db * 4];
    bf16_t* const nxt = (bf16_t*)lds[(db ^ 1) * 4];

    // ---- phase 1: khalf0, mhalf0 (+ B khalf0 reads); stage A1(kt+1)
    {
      const char* sA = (const char*)(cur);             // slot db*4+0
      const char* sB = (const char*)(cur + 2 * 8192);  // slot db*4+2
      bf16x8 af[4];
#pragma unroll
      for (int i = 0; i < 4; ++i)
        af[i] = *(const bf16x8*)(sA + ((wm * 128 + i * 16 + l15) << 6) + kbs);
#pragma unroll
      for (int i = 0; i < 4; ++i)
        bfr[i] = *(const bf16x8*)(sB + ((wn * 64 + i * 16 + l15) << 6) + kbs);
      if (p1) STAGE(aR0, aR1, (kt + 1) * 64 + 32, nxt + 1 * 8192);
      BAR();
      __builtin_amdgcn_s_setprio(1);
#pragma unroll
      for (int i = 0; i < 4; ++i)
#pragma unroll
        for (int j = 0; j < 4; ++j)
          acc[i][j] = __builtin_amdgcn_mfma_f32_16x16x32_bf16(af[i], bfr[j], acc[i][j], 0, 0, 0);
      __builtin_amdgcn_s_setprio(0);
      BAR();
    }
    // ---- phase 2: khalf0, mhalf1; stage B1(kt+1); mid-gate
    {
      const char* sA = (const char*)(cur);
      bf16x8 af[4];
#pragma unroll
      for (int i = 0; i < 4; ++i)
        af[i] = *(const bf16x8*)(sA + ((wm * 128 + (4 + i) * 16 + l15) << 6) + kbs);
      if (p1) STAGE(bR0, bR1, (kt + 1) * 64 + 32, nxt + 3 * 8192);
      BAR();
      __builtin_amdgcn_s_setprio(1);
#pragma unroll
      for (int i = 0; i < 4; ++i)
#pragma unroll
        for (int j = 0; j < 4; ++j)
          acc[4 + i][j] = __builtin_amdgcn_mfma_f32_16x16x32_bf16(af[i], bfr[j], acc[4 + i][j], 0, 0, 0);
      __builtin_amdgcn_s_setprio(0);
      if (p1) asm volatile("s_waitcnt vmcnt(8)" ::: "memory");  // A1(kt),B1(kt) landed
      else    asm volatile("s_waitcnt vmcnt(0)" ::: "memory");
      BAR();
    }
    // ---- phase 3: khalf1, mhalf0 (+ B khalf1 reads); stage A0(kt+2)
    {
      const char* sA = (const char*)(cur + 1 * 8192);  // slot db*4+1
      const char* sB = (const char*)(cur + 3 * 8192);  // slot db*4+3
      bf16x8 af[4];
#pragma unroll
      for (int i = 0; i < 4; ++i)
        af[i] = *(const bf16x8*)(sA + ((wm * 128 + i * 16 + l15) << 6) + kbs);
#pragma unroll
      for (int i = 0; i < 4; ++i)
        bfr[i] = *(const bf16x8*)(sB + ((wn * 64 + i * 16 + l15) << 6) + kbs);
      if (p2) STAGE(aR0, aR1, (kt + 2) * 64, cur + 0 * 8192);
      BAR();
      __builtin_amdgcn_s_setprio(1);
#pragma unroll
      for (int i = 0; i < 4; ++i)
#pragma unroll
        for (int j = 0; j < 4; ++j)
          acc[i][j] = __builtin_amdgcn_mfma_f32_16x16x32_bf16(af[i], bfr[j], acc[i][j], 0, 0, 0);
      __builtin_amdgcn_s_setprio(0);
      BAR();
    }
    // ---- phase 4: khalf1, mhalf1; stage B0(kt+2); end-gate
    {
      const char* sA = (const char*)(cur + 1 * 8192);
      bf16x8 af[4];
#pragma unroll
      for (int i = 0; i < 4; ++i)
        af[i] = *(const bf16x8*)(sA + ((wm * 128 + (4 + i) * 16 + l15) << 6) + kbs);
      if (p2) STAGE(bR0, bR1, (kt + 2) * 64, cur + 2 * 8192);
      BAR();
      __builtin_amdgcn_s_setprio(1);
#pragma unroll
      for (int i = 0; i < 4; ++i)
#pragma unroll
        for (int j = 0; j < 4; ++j)
          acc[4 + i][j] = __builtin_amdgcn_mfma_f32_16x16x32_bf16(af[i], bfr[j], acc[4 + i][j], 0, 0, 0);
      __builtin_amdgcn_s_setprio(0);
      if (p1) {
        if (p2) asm volatile("s_waitcnt vmcnt(8)" ::: "memory");  // A0(kt+1),B0(kt+1) landed
        else    asm volatile("s_waitcnt vmcnt(4)" ::: "memory");
      }
      BAR();
    }
  }

  // epilogue: D frag col = lane&15, row = (lane>>4)*4 + j
  const int r0 = bm * 256 + wm * 128 + ((lane >> 4) * 4);
  const int c0 = bn * 256 + wn * 64 + l15;
#pragma unroll
  for (int ni = 0; ni < 4; ++ni) {
    const int col = c0 + ni * 16;
    const float bv = (col < Nbias) ? bias[col] : 0.f;
    const bool cok = (col < Nstore);
#pragma unroll
    for (int mi = 0; mi < 8; ++mi) {
#pragma unroll
      for (int j = 0; j < 4; ++j) {
        float v = acc[mi][ni][j] + bv;
        if (ACT == ACT_RELU) v = fmaxf(v, 0.f);
        else if (ACT == ACT_REG) v = fminf(fmaxf(v + 1.f, 0.05f), 1e9f);
        if (cok) {
          const size_t off = (size_t)(r0 + mi * 16 + j) * Nstore + col;
          if (OUTMODE == 0 || OUTMODE == 2) Cb[off] = (bf16_t)v;
          if (OUTMODE == 1 || OUTMODE == 2) Cf[off] = v;
        }
      }
    }
  }
}

// ---------------------------------------------------------------- 128x128 m97-style GEMM (kept for G5, N=512)
template <int ACT, int OUTMODE>
__global__ __launch_bounds__(256)
void gemm_kernel(const bf16_t* __restrict__ A, const bf16_t* __restrict__ Bw,
                 const float* __restrict__ bias, int Nbias,
                 bf16_t* __restrict__ Cb, float* __restrict__ Cf,
                 int Kd, int Nd) {
  __shared__ __align__(16) bf16_t As[128 * 64];
  __shared__ __align__(16) bf16_t Bs[128 * 64];

  const int bn = blockIdx.x, bm = blockIdx.y;
  const int t = threadIdx.x;
  const int lane = t & 63;
  const int wv = t >> 6;
  const int wm = wv >> 1, wn = wv & 1;

  f32x4 acc[4][4];
#pragma unroll
  for (int i = 0; i < 4; ++i)
#pragma unroll
    for (int j = 0; j < 4; ++j) acc[i][j] = f32x4{0.f, 0.f, 0.f, 0.f};

  const size_t aBase = (size_t)(bm * 128) * Kd;
  const size_t bBase = (size_t)(bn * 128) * Kd;

  for (int kt = 0; kt < Kd; kt += 64) {
    __syncthreads();
#pragma unroll
    for (int q = 0; q < 4; ++q) {
      const int lin = q * 256 + t;
      const int row = lin >> 3;
      const int kc = (lin & 7) * 8;
      const int lofs = (q * 256 + wv * 64) * 16;
      gload_lds16(A + aBase + (size_t)row * Kd + kt + kc, (char*)As + lofs);
      gload_lds16(Bw + bBase + (size_t)row * Kd + kt + kc, (char*)Bs + lofs);
    }
    __syncthreads();

#pragma unroll
    for (int s = 0; s < 2; ++s) {
      const int k0 = s * 32 + ((lane >> 4) * 8);
      bf16x8 af[4], bf[4];
#pragma unroll
      for (int i = 0; i < 4; ++i) {
        const int ra = wm * 64 + i * 16 + (lane & 15);
        af[i] = *(const bf16x8*)(As + ra * 64 + k0);
        const int rb = wn * 64 + i * 16 + (lane & 15);
        bf[i] = *(const bf16x8*)(Bs + rb * 64 + k0);
      }
#pragma unroll
      for (int mi = 0; mi < 4; ++mi)
#pragma unroll
        for (int ni = 0; ni < 4; ++ni)
          acc[mi][ni] = __builtin_amdgcn_mfma_f32_16x16x32_bf16(af[mi], bf[ni], acc[mi][ni], 0, 0, 0);
    }
  }

  const int r0 = bm * 128 + wm * 64 + ((lane >> 4) * 4);
  const int c0 = bn * 128 + wn * 64 + (lane & 15);
#pragma unroll
  for (int ni = 0; ni < 4; ++ni) {
    const int col = c0 + ni * 16;
    const float bv = (col < Nbias) ? bias[col] : 0.f;
#pragma unroll
    for (int mi = 0; mi < 4; ++mi) {
#pragma unroll
      for (int j = 0; j < 4; ++j) {
        float v = acc[mi][ni][j] + bv;
        if (ACT == ACT_RELU) v = fmaxf(v, 0.f);
        else if (ACT == ACT_REG) v = fminf(fmaxf(v + 1.f, 0.05f), 1e9f);
        const size_t off = (size_t)(r0 + mi * 16 + j) * Nd + col;
        if (OUTMODE == 0 || OUTMODE == 2) Cb[off] = (bf16_t)v;
        if (OUTMODE == 1 || OUTMODE == 2) Cf[off] = v;
      }
    }
  }
}

// ---------------------------------------------------------------- softmax over K=2 + weighted combine
__global__ void combine_kernel(const float* __restrict__ L, const float* __restrict__ E,
                               float* __restrict__ out) {
  const int i = blockIdx.x * 256 + threadIdx.x;   // exact grid: BATCH*400
  const int b = i / 400;
  const int d = i - b * 400;
  const float l1 = L[(size_t)b * N5 + d];
  const float l2 = L[(size_t)(BATCH + b) * N5 + d];
  const float att1 = 1.f / (1.f + expf(l2 - l1));
  const float att2 = 1.f - att1;
  const float* E1 = E + (size_t)b * N3s;
  const float* E2 = E + (size_t)(BATCH + b) * N3s;
  out[i] = att1 * E1[d] + att2 * E2[d];                                    // alpha
  out[(size_t)BATCH * 400 + i] = att1 * E1[400 + d] + att2 * E2[400 + d];  // beta
}

// ----------------------------------------------------------------
extern "C" void kernel_launch(void* const* d_in, const int* in_sizes, int n_in,
                              void* d_out, int out_size, void* d_ws, size_t ws_size,
                              hipStream_t stream) {
  const int* a1 = (const int*)d_in[0];
  const int* r1 = (const int*)d_in[1];
  const int* a2 = (const int*)d_in[2];
  const int* r2 = (const int*)d_in[3];
  const float* ent = (const float*)d_in[4];
  const float* rel = (const float*)d_in[5];
  const float* pW1 = (const float*)d_in[6];
  const float* pb1 = (const float*)d_in[7];
  const float* pW2 = (const float*)d_in[8];
  const float* pb2 = (const float*)d_in[9];
  const float* pW0 = (const float*)d_in[10];
  const float* pb0 = (const float*)d_in[11];
  const float* iW1 = (const float*)d_in[12];
  const float* ib1 = (const float*)d_in[13];
  const float* iW2 = (const float*)d_in[14];
  const float* ib2 = (const float*)d_in[15];

  char* ws = (char*)d_ws;
  size_t o = 0;
  auto take = [&](size_t bytes) { char* p = ws + o; o += (bytes + 255) & ~(size_t)255; return p; };
  bf16_t* W1b  = (bf16_t*)take((size_t)N1c * K1 * 2);
  bf16_t* W2b  = (bf16_t*)take((size_t)N2c * K2 * 2);
  bf16_t* W0b  = (bf16_t*)take((size_t)N3c * K3 * 2);
  bf16_t* iW1b = (bf16_t*)take((size_t)N4c * K4 * 2);
  bf16_t* iW2b = (bf16_t*)take((size_t)N5 * K5 * 2);
  char* bufX = take((size_t)M * K1 * 2);   // X bf16 [M,K1]; later E bf16 [M,1024]
  char* bufY = take((size_t)M * N1s * 2);  // Y bf16 [M,1664]; later H bf16 [M,1024]
  char* bufZ = take((size_t)M * N2s * 2);  // Z bf16 [M,1664]; later L f32 [M,512]
  float* Ef  = (float*)take((size_t)M * N3s * 4);  // E f32 for combine

  bf16_t* Xb = (bf16_t*)bufX;
  bf16_t* Yb = (bf16_t*)bufY;
  bf16_t* Zb = (bf16_t*)bufZ;
  bf16_t* Eb = (bf16_t*)bufX;   // reuse: X dead after G1
  bf16_t* Hb = (bf16_t*)bufY;   // reuse: Y dead after G2
  float*  Lf = (float*)bufZ;    // reuse: Z dead after G3

  auto cgrid = [](int n4) { return dim3((n4 + 255) / 256); };
  convw_kernel<<<cgrid(N1c * K1 / 4), 256, 0, stream>>>(pW1, W1b, 1600, 1200, K1, N1c * K1 / 4);
  convw_kernel<<<cgrid(N2c * K2 / 4), 256, 0, stream>>>(pW2, W2b, 1600, 1600, K2, N2c * K2 / 4);
  convw_kernel<<<cgrid(N3c * K3 / 4), 256, 0, stream>>>(pW0, W0b, 800, 1600, K3, N3c * K3 / 4);
  convw_kernel<<<cgrid(N4c * K4 / 4), 256, 0, stream>>>(iW1, iW1b, 800, 800, K4, N4c * K4 / 4);
  convw_kernel<<<cgrid(N5 * K5 / 4), 256, 0, stream>>>(iW2, iW2b, 400, 800, K5, N5 * K5 / 4);

  gather_kernel<<<M, 256, 0, stream>>>(a1, r1, a2, r2, ent, rel, Xb);

  // G1: Y = relu(X W1^T + b1)   [16384 x 1792(k1216)] store 1664
  gemm256<ACT_RELU, 0><<<dim3((N1c / 256) * (M / 256)), 512, 0, stream>>>(
      Xb, W1b, pb1, 1600, Yb, nullptr, K1, N1s, K1 / 64, N1c / 256);
  // G2: Z = relu(Y W2^T + b2)   [16384 x 1792(k1664)] store 1664
  gemm256<ACT_RELU, 0><<<dim3((N2c / 256) * (M / 256)), 512, 0, stream>>>(
      Yb, W2b, pb2, 1600, Zb, nullptr, K2, N2s, K2 / 64, N2c / 256);
  // G3: E = reg(Z W0^T + b0)    [16384 x 1024(k1664)] -> bf16 + f32
  gemm256<ACT_REG, 2><<<dim3((N3c / 256) * (M / 256)), 512, 0, stream>>>(
      Zb, W0b, pb0, 800, Eb, Ef, K3, N3s, K3 / 64, N3c / 256);
  // G4: H = relu(E iW1^T + ib1) [16384 x 1024(k1024)]
  gemm256<ACT_RELU, 0><<<dim3((N4c / 256) * (M / 256)), 512, 0, stream>>>(
      Eb, iW1b, ib1, 800, Hb, nullptr, K4, N4s, K4 / 64, N4c / 256);
  // G5: L = H iW2^T + ib2 (f32 logits) — small N, old 128^2 kernel
  gemm_kernel<ACT_NONE, 1><<<dim3(N5 / 128, M / 128), 256, 0, stream>>>(
      Hb, iW2b, ib2, 400, nullptr, Lf, K5, N5);

  combine_kernel<<<(BATCH * 400) / 256, 256, 0, stream>>>(Lf, Ef, (float*)d_out);
}

// Round 3
// 367.840 us; speedup vs baseline: 1.4140x; 1.1382x over previous
//
#include <hip/hip_runtime.h>
#include <hip/hip_bf16.h>
#include <stdint.h>

typedef __bf16 bf16_t;
typedef __bf16 bf16x8 __attribute__((ext_vector_type(8)));
typedef float f32x4 __attribute__((ext_vector_type(4)));

constexpr int BATCH = 8192;
constexpr int M = 2 * BATCH;          // both branches stacked: 16384 rows

// GEMM dims: compute-N padded to 256, store width = next lda (multiple of 64)
constexpr int K1 = 1216;                    // [e|r] 1200 -> 1216 (X zero-padded)
constexpr int N1c = 1792, N1s = 1664;       // H 1600: compute 1792, store 1664
constexpr int LDA2 = 1664, KL2 = 1600;      // G2: stride 1664, loop 1600 (cols>=1600 are 0)
constexpr int N2c = 1792, N2s = 1664;
constexpr int LDA3 = 1664, KL3 = 1600;
constexpr int N3c = 1024, N3s = 1024;       // 2d 800 -> 1024
constexpr int LDA4 = 1024, KL4 = 832;       // E cols>=800 hit zero weight k-cols
constexpr int N4c = 1024, N4s = 1024;
constexpr int LDA5 = 1024, KL5 = 832, N5 = 512;

// ---------------------------------------------------------------- staging
__device__ __forceinline__ void gload_lds16(const void* g, void* l) {
  __builtin_amdgcn_global_load_lds(
      (const __attribute__((address_space(1))) void*)g,
      (__attribute__((address_space(3))) void*)l,
      16, 0, 0);
}

#define CFENCE() asm volatile("" ::: "memory")
#define BAR()  { CFENCE(); __builtin_amdgcn_s_barrier(); CFENCE(); }

// ---------------------------------------------------------------- gather + reg + concat -> bf16 X [M, K1]
__global__ void gather_kernel(const int* __restrict__ a1, const int* __restrict__ r1,
                              const int* __restrict__ a2, const int* __restrict__ r2,
                              const float* __restrict__ ent, const float* __restrict__ rel,
                              bf16_t* __restrict__ X) {
  const int row = blockIdx.x;            // 0..M-1
  const int b   = row & (BATCH - 1);
  const int br  = row >> 13;             // 0: branch1, 1: branch2
  const int eidx = br ? a2[b] : a1[b];
  const int ridx = br ? r2[b] : r1[b];
  const float* __restrict__ esrc = ent + (size_t)eidx * 800;
  const float* __restrict__ rsrc = rel + (size_t)ridx * 400;
  bf16_t* __restrict__ dst = X + (size_t)row * K1;

  for (int g = threadIdx.x; g < K1 / 4; g += 256) {
    const int c = g * 4;
    float4 v = make_float4(0.f, 0.f, 0.f, 0.f);
    if (c < 800) {                       // entity part: _reg = clip(x+1, 0.05, 1e9)
      v = *(const float4*)(esrc + c);
      v.x = fminf(fmaxf(v.x + 1.f, 0.05f), 1e9f);
      v.y = fminf(fmaxf(v.y + 1.f, 0.05f), 1e9f);
      v.z = fminf(fmaxf(v.z + 1.f, 0.05f), 1e9f);
      v.w = fminf(fmaxf(v.w + 1.f, 0.05f), 1e9f);
    } else if (c < 1200) {               // relation part (no reg)
      v = *(const float4*)(rsrc + (c - 800));
    }                                    // else zero pad
    union { bf16_t h[4]; uint2 u; } pk;
    pk.h[0] = (bf16_t)v.x; pk.h[1] = (bf16_t)v.y;
    pk.h[2] = (bf16_t)v.z; pk.h[3] = (bf16_t)v.w;
    *(uint2*)(dst + c) = pk.u;
  }
}

// ---------------------------------------------------------------- all 5 weight conversions, one launch
__device__ __forceinline__ void doconv(int idx, const float* __restrict__ src,
                                       bf16_t* __restrict__ dst, int Nr, int Kc, int Kp) {
  const int kp4 = Kp >> 2;
  const int r = idx / kp4;
  const int c = (idx - r * kp4) << 2;
  union { bf16_t h[4]; uint2 u; } pk;
#pragma unroll
  for (int j = 0; j < 4; ++j) {
    const int cc = c + j;
    const float v = (r < Nr && cc < Kc) ? src[(size_t)r * Kc + cc] : 0.f;
    pk.h[j] = (bf16_t)v;
  }
  *(uint2*)(dst + (size_t)r * Kp + c) = pk.u;
}

constexpr int CJ0 = N1c * K1 / 4;            // 544768
constexpr int CJ1 = CJ0 + N2c * LDA2 / 4;    // +745472
constexpr int CJ2 = CJ1 + N3c * LDA3 / 4;    // +425984
constexpr int CJ3 = CJ2 + N4c * LDA4 / 4;    // +262144
constexpr int CJ4 = CJ3 + N5 * LDA5 / 4;     // +131072 -> 2109440 (/256 = 8240)

__global__ void convw5_kernel(const float* __restrict__ pW1, const float* __restrict__ pW2,
                              const float* __restrict__ pW0, const float* __restrict__ iW1,
                              const float* __restrict__ iW2,
                              bf16_t* __restrict__ W1b, bf16_t* __restrict__ W2b,
                              bf16_t* __restrict__ W0b, bf16_t* __restrict__ iW1b,
                              bf16_t* __restrict__ iW2b) {
  int idx = blockIdx.x * 256 + threadIdx.x;
  if (idx < CJ0)      doconv(idx,        pW1, W1b, 1600, 1200, K1);
  else if (idx < CJ1) doconv(idx - CJ0,  pW2, W2b, 1600, 1600, LDA2);
  else if (idx < CJ2) doconv(idx - CJ1,  pW0, W0b,  800, 1600, LDA3);
  else if (idx < CJ3) doconv(idx - CJ2,  iW1, iW1b, 800,  800, LDA4);
  else                doconv(idx - CJ3,  iW2, iW2b, 400,  800, LDA5);
}

enum { ACT_RELU = 0, ACT_REG = 1, ACT_NONE = 2 };

// ---------------------------------------------------------------- 256x256 8-phase pipelined GEMM
// C[M,*] = act(A[M,*lda] * B[Nc,*lda]^T + bias); 512 thr = 8 waves (2m x 4n), BK=64.
// LDS: 8 slots of [256 rows][32 k] bf16 = 128 KiB. Swizzle: chunk pos = g ^ ((row>>1)&3)
// -> 16-lane read group spans all 8 bank-quads over 8 rows = 2-way (free, m136).
// Gates: vmcnt(8) at end of ph2 and ph4 (counted, never 0 mid-loop); raw s_barrier only.
template <int ACT, int OUTMODE>   // OUTMODE: 0 = bf16, 1 = f32, 2 = both
__global__ __launch_bounds__(512)
void gemm256(const bf16_t* __restrict__ A, const bf16_t* __restrict__ Bw,
             const float* __restrict__ bias, int Nbias,
             bf16_t* __restrict__ Cb, float* __restrict__ Cf,
             int lda, int Nstore, int NT, int gridN) {
  __shared__ __align__(16) bf16_t lds[8][8192];

  const int nwg = gridDim.x;
  const int id = blockIdx.x;
  const int swz = (id & 7) * (nwg >> 3) + (id >> 3);   // XCD-aware (nwg % 8 == 0)
  const int bn = swz % gridN, bm = swz / gridN;

  const int t = threadIdx.x;
  const int lane = t & 63;
  const int wv = t >> 6;
  const int wm = wv >> 2, wn = wv & 3;
  const int l15 = lane & 15;
  // read: lane group q=lane>>4 wants global chunk q of row (..+l15); stored at pos q ^ ((row>>1)&3)
  const int kbs = (((lane >> 4) ^ ((l15 >> 1) & 3)) << 4);

  // staging: thread t writes LDS chunk t (row t>>2, pos t&3) -> source global chunk (t&3)^((t>>3)&3)
  const int srow = t >> 2;
  const int skc  = (t & 3) ^ ((t >> 3) & 3);
  const bf16_t* aR0 = A  + (size_t)(bm * 256 + srow) * lda + skc * 8;
  const bf16_t* aR1 = aR0 + (size_t)128 * lda;
  const bf16_t* bR0 = Bw + (size_t)(bn * 256 + srow) * lda + skc * 8;
  const bf16_t* bR1 = bR0 + (size_t)128 * lda;
  const int ldsb0 = (wv * 64) * 16;
  const int ldsb1 = (512 + wv * 64) * 16;

  auto STAGE = [&](const bf16_t* r0p, const bf16_t* r1p, int kOff, bf16_t* slot) {
    gload_lds16(r0p + kOff, (char*)slot + ldsb0);
    gload_lds16(r1p + kOff, (char*)slot + ldsb1);
  };

  f32x4 acc[8][4];
#pragma unroll
  for (int i = 0; i < 8; ++i)
#pragma unroll
    for (int j = 0; j < 4; ++j) acc[i][j] = f32x4{0.f, 0.f, 0.f, 0.f};

  // prologue: tile0 (4 slots) + tile1 k-half0 (2 slots)
  STAGE(aR0, aR1, 0, lds[0]);
  STAGE(bR0, bR1, 0, lds[2]);
  STAGE(aR0, aR1, 32, lds[1]);
  STAGE(bR0, bR1, 32, lds[3]);
  if (NT > 1) {
    STAGE(aR0, aR1, 64, lds[4]);
    STAGE(bR0, bR1, 64, lds[6]);
    asm volatile("s_waitcnt vmcnt(8)" ::: "memory");   // A0(0),B0(0) landed
  } else {
    asm volatile("s_waitcnt vmcnt(4)" ::: "memory");
  }
  __builtin_amdgcn_s_barrier();
  CFENCE();

  bf16x8 bfr[4];
  int db = 0;
  for (int kt = 0; kt < NT; ++kt, db ^= 1) {
    const bool p1 = (kt + 1) < NT;
    const bool p2 = (kt + 2) < NT;
    bf16_t* const cur = (bf16_t*)lds[db * 4];
    bf16_t* const nxt = (bf16_t*)lds[(db ^ 1) * 4];

    // ---- phase 1: khalf0, mhalf0 (+ B khalf0 reads); stage A1(kt+1)
    {
      const char* sA = (const char*)(cur);             // slot db*4+0
      const char* sB = (const char*)(cur + 2 * 8192);  // slot db*4+2
      bf16x8 af[4];
#pragma unroll
      for (int i = 0; i < 4; ++i)
        af[i] = *(const bf16x8*)(sA + ((wm * 128 + i * 16 + l15) << 6) + kbs);
#pragma unroll
      for (int i = 0; i < 4; ++i)
        bfr[i] = *(const bf16x8*)(sB + ((wn * 64 + i * 16 + l15) << 6) + kbs);
      if (p1) STAGE(aR0, aR1, (kt + 1) * 64 + 32, nxt + 1 * 8192);
      BAR();
      __builtin_amdgcn_s_setprio(1);
#pragma unroll
      for (int i = 0; i < 4; ++i)
#pragma unroll
        for (int j = 0; j < 4; ++j)
          acc[i][j] = __builtin_amdgcn_mfma_f32_16x16x32_bf16(af[i], bfr[j], acc[i][j], 0, 0, 0);
      __builtin_amdgcn_s_setprio(0);
      BAR();
    }
    // ---- phase 2: khalf0, mhalf1; stage B1(kt+1); mid-gate
    {
      const char* sA = (const char*)(cur);
      bf16x8 af[4];
#pragma unroll
      for (int i = 0; i < 4; ++i)
        af[i] = *(const bf16x8*)(sA + ((wm * 128 + (4 + i) * 16 + l15) << 6) + kbs);
      if (p1) STAGE(bR0, bR1, (kt + 1) * 64 + 32, nxt + 3 * 8192);
      BAR();
      __builtin_amdgcn_s_setprio(1);
#pragma unroll
      for (int i = 0; i < 4; ++i)
#pragma unroll
        for (int j = 0; j < 4; ++j)
          acc[4 + i][j] = __builtin_amdgcn_mfma_f32_16x16x32_bf16(af[i], bfr[j], acc[4 + i][j], 0, 0, 0);
      __builtin_amdgcn_s_setprio(0);
      if (p1) asm volatile("s_waitcnt vmcnt(8)" ::: "memory");  // A1(kt),B1(kt) landed
      else    asm volatile("s_waitcnt vmcnt(0)" ::: "memory");
      BAR();
    }
    // ---- phase 3: khalf1, mhalf0 (+ B khalf1 reads); stage A0(kt+2)
    {
      const char* sA = (const char*)(cur + 1 * 8192);  // slot db*4+1
      const char* sB = (const char*)(cur + 3 * 8192);  // slot db*4+3
      bf16x8 af[4];
#pragma unroll
      for (int i = 0; i < 4; ++i)
        af[i] = *(const bf16x8*)(sA + ((wm * 128 + i * 16 + l15) << 6) + kbs);
#pragma unroll
      for (int i = 0; i < 4; ++i)
        bfr[i] = *(const bf16x8*)(sB + ((wn * 64 + i * 16 + l15) << 6) + kbs);
      if (p2) STAGE(aR0, aR1, (kt + 2) * 64, cur + 0 * 8192);
      BAR();
      __builtin_amdgcn_s_setprio(1);
#pragma unroll
      for (int i = 0; i < 4; ++i)
#pragma unroll
        for (int j = 0; j < 4; ++j)
          acc[i][j] = __builtin_amdgcn_mfma_f32_16x16x32_bf16(af[i], bfr[j], acc[i][j], 0, 0, 0);
      __builtin_amdgcn_s_setprio(0);
      BAR();
    }
    // ---- phase 4: khalf1, mhalf1; stage B0(kt+2); end-gate
    {
      const char* sA = (const char*)(cur + 1 * 8192);
      bf16x8 af[4];
#pragma unroll
      for (int i = 0; i < 4; ++i)
        af[i] = *(const bf16x8*)(sA + ((wm * 128 + (4 + i) * 16 + l15) << 6) + kbs);
      if (p2) STAGE(bR0, bR1, (kt + 2) * 64, cur + 2 * 8192);
      BAR();
      __builtin_amdgcn_s_setprio(1);
#pragma unroll
      for (int i = 0; i < 4; ++i)
#pragma unroll
        for (int j = 0; j < 4; ++j)
          acc[4 + i][j] = __builtin_amdgcn_mfma_f32_16x16x32_bf16(af[i], bfr[j], acc[4 + i][j], 0, 0, 0);
      __builtin_amdgcn_s_setprio(0);
      if (p1) {
        if (p2) asm volatile("s_waitcnt vmcnt(8)" ::: "memory");  // A0(kt+1),B0(kt+1) landed
        else    asm volatile("s_waitcnt vmcnt(4)" ::: "memory");
      }
      BAR();
    }
  }

  // epilogue: D frag col = lane&15, row = (lane>>4)*4 + j
  const int r0 = bm * 256 + wm * 128 + ((lane >> 4) * 4);
  const int c0 = bn * 256 + wn * 64 + l15;
#pragma unroll
  for (int ni = 0; ni < 4; ++ni) {
    const int col = c0 + ni * 16;
    const float bv = (col < Nbias) ? bias[col] : 0.f;
    const bool cok = (col < Nstore);
#pragma unroll
    for (int mi = 0; mi < 8; ++mi) {
#pragma unroll
      for (int j = 0; j < 4; ++j) {
        float v = acc[mi][ni][j] + bv;
        if (ACT == ACT_RELU) v = fmaxf(v, 0.f);
        else if (ACT == ACT_REG) v = fminf(fmaxf(v + 1.f, 0.05f), 1e9f);
        if (cok) {
          const size_t off = (size_t)(r0 + mi * 16 + j) * Nstore + col;
          if (OUTMODE == 0 || OUTMODE == 2) Cb[off] = (bf16_t)v;
          if (OUTMODE == 1 || OUTMODE == 2) Cf[off] = v;
        }
      }
    }
  }
}

// ---------------------------------------------------------------- 128x128 m97-style GEMM (G5, N=512)
// LDS swizzle: row stride 128B was a 16-way conflict; chunk pos = g ^ (row&7) -> 2-way.
template <int ACT, int OUTMODE>
__global__ __launch_bounds__(256)
void gemm_kernel(const bf16_t* __restrict__ A, const bf16_t* __restrict__ Bw,
                 const float* __restrict__ bias, int Nbias,
                 bf16_t* __restrict__ Cb, float* __restrict__ Cf,
                 int lda, int Kloop, int Nd) {
  __shared__ __align__(16) bf16_t As[128 * 64];
  __shared__ __align__(16) bf16_t Bs[128 * 64];

  const int bn = blockIdx.x, bm = blockIdx.y;
  const int t = threadIdx.x;
  const int lane = t & 63;
  const int wv = t >> 6;
  const int wm = wv >> 1, wn = wv & 1;

  f32x4 acc[4][4];
#pragma unroll
  for (int i = 0; i < 4; ++i)
#pragma unroll
    for (int j = 0; j < 4; ++j) acc[i][j] = f32x4{0.f, 0.f, 0.f, 0.f};

  const size_t aBase = (size_t)(bm * 128) * lda;
  const size_t bBase = (size_t)(bn * 128) * lda;

  for (int kt = 0; kt < Kloop; kt += 64) {
    __syncthreads();
#pragma unroll
    for (int q = 0; q < 4; ++q) {
      const int lin = q * 256 + t;
      const int row = lin >> 3;
      const int kc = ((lin & 7) ^ ((lin >> 3) & 7)) * 8;   // swizzled source chunk
      const int lofs = (q * 256 + wv * 64) * 16;
      gload_lds16(A + aBase + (size_t)row * lda + kt + kc, (char*)As + lofs);
      gload_lds16(Bw + bBase + (size_t)row * lda + kt + kc, (char*)Bs + lofs);
    }
    __syncthreads();

#pragma unroll
    for (int s = 0; s < 2; ++s) {
      const int crd = s * 4 + (lane >> 4);
      const int k0 = (crd ^ (lane & 7)) * 8;               // swizzled read chunk
      bf16x8 af[4], bf[4];
#pragma unroll
      for (int i = 0; i < 4; ++i) {
        const int ra = wm * 64 + i * 16 + (lane & 15);
        af[i] = *(const bf16x8*)(As + ra * 64 + k0);
        const int rb = wn * 64 + i * 16 + (lane & 15);
        bf[i] = *(const bf16x8*)(Bs + rb * 64 + k0);
      }
#pragma unroll
      for (int mi = 0; mi < 4; ++mi)
#pragma unroll
        for (int ni = 0; ni < 4; ++ni)
          acc[mi][ni] = __builtin_amdgcn_mfma_f32_16x16x32_bf16(af[mi], bf[ni], acc[mi][ni], 0, 0, 0);
    }
  }

  const int r0 = bm * 128 + wm * 64 + ((lane >> 4) * 4);
  const int c0 = bn * 128 + wn * 64 + (lane & 15);
#pragma unroll
  for (int ni = 0; ni < 4; ++ni) {
    const int col = c0 + ni * 16;
    const float bv = (col < Nbias) ? bias[col] : 0.f;
#pragma unroll
    for (int mi = 0; mi < 4; ++mi) {
#pragma unroll
      for (int j = 0; j < 4; ++j) {
        float v = acc[mi][ni][j] + bv;
        if (ACT == ACT_RELU) v = fmaxf(v, 0.f);
        else if (ACT == ACT_REG) v = fminf(fmaxf(v + 1.f, 0.05f), 1e9f);
        const size_t off = (size_t)(r0 + mi * 16 + j) * Nd + col;
        if (OUTMODE == 0 || OUTMODE == 2) Cb[off] = (bf16_t)v;
        if (OUTMODE == 1 || OUTMODE == 2) Cf[off] = v;
      }
    }
  }
}

// ---------------------------------------------------------------- softmax over K=2 + weighted combine
__global__ void combine_kernel(const float* __restrict__ L, const float* __restrict__ E,
                               float* __restrict__ out) {
  const int i = blockIdx.x * 256 + threadIdx.x;   // exact grid: BATCH*400
  const int b = i / 400;
  const int d = i - b * 400;
  const float l1 = L[(size_t)b * N5 + d];
  const float l2 = L[(size_t)(BATCH + b) * N5 + d];
  const float att1 = 1.f / (1.f + expf(l2 - l1));
  const float att2 = 1.f - att1;
  const float* E1 = E + (size_t)b * N3s;
  const float* E2 = E + (size_t)(BATCH + b) * N3s;
  out[i] = att1 * E1[d] + att2 * E2[d];                                    // alpha
  out[(size_t)BATCH * 400 + i] = att1 * E1[400 + d] + att2 * E2[400 + d];  // beta
}

// ----------------------------------------------------------------
extern "C" void kernel_launch(void* const* d_in, const int* in_sizes, int n_in,
                              void* d_out, int out_size, void* d_ws, size_t ws_size,
                              hipStream_t stream) {
  const int* a1 = (const int*)d_in[0];
  const int* r1 = (const int*)d_in[1];
  const int* a2 = (const int*)d_in[2];
  const int* r2 = (const int*)d_in[3];
  const float* ent = (const float*)d_in[4];
  const float* rel = (const float*)d_in[5];
  const float* pW1 = (const float*)d_in[6];
  const float* pb1 = (const float*)d_in[7];
  const float* pW2 = (const float*)d_in[8];
  const float* pb2 = (const float*)d_in[9];
  const float* pW0 = (const float*)d_in[10];
  const float* pb0 = (const float*)d_in[11];
  const float* iW1 = (const float*)d_in[12];
  const float* ib1 = (const float*)d_in[13];
  const float* iW2 = (const float*)d_in[14];
  const float* ib2 = (const float*)d_in[15];

  char* ws = (char*)d_ws;
  size_t o = 0;
  auto take = [&](size_t bytes) { char* p = ws + o; o += (bytes + 255) & ~(size_t)255; return p; };
  bf16_t* W1b  = (bf16_t*)take((size_t)N1c * K1 * 2);
  bf16_t* W2b  = (bf16_t*)take((size_t)N2c * LDA2 * 2);
  bf16_t* W0b  = (bf16_t*)take((size_t)N3c * LDA3 * 2);
  bf16_t* iW1b = (bf16_t*)take((size_t)N4c * LDA4 * 2);
  bf16_t* iW2b = (bf16_t*)take((size_t)N5 * LDA5 * 2);
  char* bufX = take((size_t)M * K1 * 2);   // X bf16 [M,1216]; later E bf16 [M,1024]
  char* bufY = take((size_t)M * N1s * 2);  // Y bf16 [M,1664]; later H bf16 [M,1024]
  char* bufZ = take((size_t)M * N2s * 2);  // Z bf16 [M,1664]; later L f32 [M,512]
  float* Ef  = (float*)take((size_t)M * N3s * 4);  // E f32 for combine

  bf16_t* Xb = (bf16_t*)bufX;
  bf16_t* Yb = (bf16_t*)bufY;
  bf16_t* Zb = (bf16_t*)bufZ;
  bf16_t* Eb = (bf16_t*)bufX;   // reuse: X dead after G1
  bf16_t* Hb = (bf16_t*)bufY;   // reuse: Y dead after G2
  float*  Lf = (float*)bufZ;    // reuse: Z dead after G3

  convw5_kernel<<<dim3(CJ4 / 256), 256, 0, stream>>>(pW1, pW2, pW0, iW1, iW2,
                                                     W1b, W2b, W0b, iW1b, iW2b);

  gather_kernel<<<M, 256, 0, stream>>>(a1, r1, a2, r2, ent, rel, Xb);

  // G1: Y = relu(X W1^T + b1)   [16384 x 1792] k=1216, store 1664
  gemm256<ACT_RELU, 0><<<dim3((N1c / 256) * (M / 256)), 512, 0, stream>>>(
      Xb, W1b, pb1, 1600, Yb, nullptr, K1, N1s, K1 / 64, N1c / 256);
  // G2: Z = relu(Y W2^T + b2)   [16384 x 1792] lda=1664, kloop=1600, store 1664
  gemm256<ACT_RELU, 0><<<dim3((N2c / 256) * (M / 256)), 512, 0, stream>>>(
      Yb, W2b, pb2, 1600, Zb, nullptr, LDA2, N2s, KL2 / 64, N2c / 256);
  // G3: E = reg(Z W0^T + b0)    [16384 x 1024] lda=1664, kloop=1600 -> bf16 + f32
  gemm256<ACT_REG, 2><<<dim3((N3c / 256) * (M / 256)), 512, 0, stream>>>(
      Zb, W0b, pb0, 800, Eb, Ef, LDA3, N3s, KL3 / 64, N3c / 256);
  // G4: H = relu(E iW1^T + ib1) [16384 x 1024] lda=1024, kloop=832
  gemm256<ACT_RELU, 0><<<dim3((N4c / 256) * (M / 256)), 512, 0, stream>>>(
      Eb, iW1b, ib1, 800, Hb, nullptr, LDA4, N4s, KL4 / 64, N4c / 256);
  // G5: L = H iW2^T + ib2 (f32 logits) — small N, 128^2 kernel, lda=1024 kloop=832
  gemm_kernel<ACT_NONE, 1><<<dim3(N5 / 128, M / 128), 256, 0, stream>>>(
      Hb, iW2b, ib2, 400, nullptr, Lf, LDA5, KL5, N5);

  combine_kernel<<<(BATCH * 400) / 256, 256, 0, stream>>>(Lf, Ef, (float*)d_out);
}

// Round 4
// 348.695 us; speedup vs baseline: 1.4917x; 1.0549x over previous
//
#include <hip/hip_runtime.h>
#include <hip/hip_bf16.h>
#include <stdint.h>

typedef __bf16 bf16_t;
typedef __bf16 bf16x8 __attribute__((ext_vector_type(8)));
typedef float f32x4 __attribute__((ext_vector_type(4)));

constexpr int BATCH = 8192;
constexpr int M = 2 * BATCH;          // both branches stacked: 16384 rows

// GEMM dims: compute-N padded to 256, store width trimmed to what's read downstream
constexpr int K1 = 1216;                    // [e|r] 1200 -> 1216 (X zero-padded)
constexpr int N1c = 1792;                   // H 1600 -> 1792 compute
constexpr int LDC1 = 1664, NS1 = 1600;      // Y: stride 1664, store cols<1600
constexpr int LDA2 = 1664, KL2 = 1600;
constexpr int N2c = 1792;
constexpr int LDC2 = 1664, NS2 = 1600;
constexpr int LDA3 = 1664, KL3 = 1600;
constexpr int N3c = 1024;                   // 2d 800 -> 1024 compute
constexpr int LDC3 = 1024, NS3 = 832;       // E: only cols<832 read (weights zero past 800)
constexpr int LDA4 = 1024, KL4 = 832;
constexpr int N4c = 1024;
constexpr int LDC4 = 1024, NS4 = 832;       // H: only cols<832 read by G5
constexpr int LDA5 = 1024, KL5 = 832, N5 = 512;

// ---------------------------------------------------------------- staging
__device__ __forceinline__ void gload_lds16(const void* g, void* l) {
  __builtin_amdgcn_global_load_lds(
      (const __attribute__((address_space(1))) void*)g,
      (__attribute__((address_space(3))) void*)l,
      16, 0, 0);
}

#define CFENCE() asm volatile("" ::: "memory")
#define BAR()  { CFENCE(); __builtin_amdgcn_s_barrier(); CFENCE(); }

// ---------------------------------------------------------------- prep: gather+reg+concat AND 5 weight converts
__device__ __forceinline__ void doconv(int idx, const float* __restrict__ src,
                                       bf16_t* __restrict__ dst, int Nr, int Kc, int Kp) {
  const int kp4 = Kp >> 2;
  const int r = idx / kp4;
  const int c = (idx - r * kp4) << 2;
  union { bf16_t h[4]; uint2 u; } pk;
#pragma unroll
  for (int j = 0; j < 4; ++j) {
    const int cc = c + j;
    const float v = (r < Nr && cc < Kc) ? src[(size_t)r * Kc + cc] : 0.f;
    pk.h[j] = (bf16_t)v;
  }
  *(uint2*)(dst + (size_t)r * Kp + c) = pk.u;
}

constexpr int CJ0 = N1c * K1 / 4;
constexpr int CJ1 = CJ0 + N2c * LDA2 / 4;
constexpr int CJ2 = CJ1 + N3c * LDA3 / 4;
constexpr int CJ3 = CJ2 + N4c * LDA4 / 4;
constexpr int CJ4 = CJ3 + N5 * LDA5 / 4;     // total conv work items
constexpr int CONV_BLOCKS = CJ4 / 256;       // 8240
constexpr int PREP_BLOCKS = M + CONV_BLOCKS; // 16384 gather blocks + conv blocks

__global__ void prep_kernel(const int* __restrict__ a1, const int* __restrict__ r1,
                            const int* __restrict__ a2, const int* __restrict__ r2,
                            const float* __restrict__ ent, const float* __restrict__ rel,
                            bf16_t* __restrict__ X,
                            const float* __restrict__ pW1, const float* __restrict__ pW2,
                            const float* __restrict__ pW0, const float* __restrict__ iW1,
                            const float* __restrict__ iW2,
                            bf16_t* __restrict__ W1b, bf16_t* __restrict__ W2b,
                            bf16_t* __restrict__ W0b, bf16_t* __restrict__ iW1b,
                            bf16_t* __restrict__ iW2b) {
  if (blockIdx.x < M) {
    const int row = blockIdx.x;
    const int b   = row & (BATCH - 1);
    const int br  = row >> 13;
    const int eidx = br ? a2[b] : a1[b];
    const int ridx = br ? r2[b] : r1[b];
    const float* __restrict__ esrc = ent + (size_t)eidx * 800;
    const float* __restrict__ rsrc = rel + (size_t)ridx * 400;
    bf16_t* __restrict__ dst = X + (size_t)row * K1;
    for (int g = threadIdx.x; g < K1 / 4; g += 256) {
      const int c = g * 4;
      float4 v = make_float4(0.f, 0.f, 0.f, 0.f);
      if (c < 800) {                       // entity: _reg = clip(x+1, 0.05, 1e9)
        v = *(const float4*)(esrc + c);
        v.x = fminf(fmaxf(v.x + 1.f, 0.05f), 1e9f);
        v.y = fminf(fmaxf(v.y + 1.f, 0.05f), 1e9f);
        v.z = fminf(fmaxf(v.z + 1.f, 0.05f), 1e9f);
        v.w = fminf(fmaxf(v.w + 1.f, 0.05f), 1e9f);
      } else if (c < 1200) {
        v = *(const float4*)(rsrc + (c - 800));
      }
      union { bf16_t h[4]; uint2 u; } pk;
      pk.h[0] = (bf16_t)v.x; pk.h[1] = (bf16_t)v.y;
      pk.h[2] = (bf16_t)v.z; pk.h[3] = (bf16_t)v.w;
      *(uint2*)(dst + c) = pk.u;
    }
  } else {
    const int idx = (blockIdx.x - M) * 256 + threadIdx.x;
    if (idx < CJ0)      doconv(idx,        pW1, W1b, 1600, 1200, K1);
    else if (idx < CJ1) doconv(idx - CJ0,  pW2, W2b, 1600, 1600, LDA2);
    else if (idx < CJ2) doconv(idx - CJ1,  pW0, W0b,  800, 1600, LDA3);
    else if (idx < CJ3) doconv(idx - CJ2,  iW1, iW1b, 800,  800, LDA4);
    else if (idx < CJ4) doconv(idx - CJ3,  iW2, iW2b, 400,  800, LDA5);
  }
}

enum { ACT_RELU = 0, ACT_REG = 1 };

// ---------------------------------------------------------------- 256x256 8-phase pipelined GEMM
// LDS: 8 slots of [256 rows][32 k] bf16 = 128 KiB. Swizzle: chunk pos = g ^ ((row>>1)&3)
// -> 16-lane read group spans all 8 bank-quads over 8 rows = 2-way (free, m136).
// Gates: vmcnt(8) at end of ph2 and ph4 (counted, never 0 mid-loop); raw s_barrier only.
template <int ACT>
__global__ __launch_bounds__(512)
void gemm256(const bf16_t* __restrict__ A, const bf16_t* __restrict__ Bw,
             const float* __restrict__ bias, int Nbias,
             bf16_t* __restrict__ Cb,
             int lda, int Nstore, int ldc, int NT, int gridN) {
  __shared__ __align__(16) bf16_t lds[8][8192];

  const int nwg = gridDim.x;
  const int id = blockIdx.x;
  const int swz = (id & 7) * (nwg >> 3) + (id >> 3);   // XCD-aware (nwg % 8 == 0)
  const int bn = swz % gridN, bm = swz / gridN;

  const int t = threadIdx.x;
  const int lane = t & 63;
  const int wv = t >> 6;
  const int wm = wv >> 2, wn = wv & 3;
  const int l15 = lane & 15;
  const int kbs = (((lane >> 4) ^ ((l15 >> 1) & 3)) << 4);

  const int srow = t >> 2;
  const int skc  = (t & 3) ^ ((t >> 3) & 3);
  const bf16_t* aR0 = A  + (size_t)(bm * 256 + srow) * lda + skc * 8;
  const bf16_t* aR1 = aR0 + (size_t)128 * lda;
  const bf16_t* bR0 = Bw + (size_t)(bn * 256 + srow) * lda + skc * 8;
  const bf16_t* bR1 = bR0 + (size_t)128 * lda;
  const int ldsb0 = (wv * 64) * 16;
  const int ldsb1 = (512 + wv * 64) * 16;

  auto STAGE = [&](const bf16_t* r0p, const bf16_t* r1p, int kOff, bf16_t* slot) {
    gload_lds16(r0p + kOff, (char*)slot + ldsb0);
    gload_lds16(r1p + kOff, (char*)slot + ldsb1);
  };

  f32x4 acc[8][4];
#pragma unroll
  for (int i = 0; i < 8; ++i)
#pragma unroll
    for (int j = 0; j < 4; ++j) acc[i][j] = f32x4{0.f, 0.f, 0.f, 0.f};

  STAGE(aR0, aR1, 0, lds[0]);
  STAGE(bR0, bR1, 0, lds[2]);
  STAGE(aR0, aR1, 32, lds[1]);
  STAGE(bR0, bR1, 32, lds[3]);
  if (NT > 1) {
    STAGE(aR0, aR1, 64, lds[4]);
    STAGE(bR0, bR1, 64, lds[6]);
    asm volatile("s_waitcnt vmcnt(8)" ::: "memory");
  } else {
    asm volatile("s_waitcnt vmcnt(4)" ::: "memory");
  }
  __builtin_amdgcn_s_barrier();
  CFENCE();

  bf16x8 bfr[4];
  int db = 0;
  for (int kt = 0; kt < NT; ++kt, db ^= 1) {
    const bool p1 = (kt + 1) < NT;
    const bool p2 = (kt + 2) < NT;
    bf16_t* const cur = (bf16_t*)lds[db * 4];
    bf16_t* const nxt = (bf16_t*)lds[(db ^ 1) * 4];

    // ---- phase 1: khalf0, mhalf0 (+ B khalf0 reads); stage A1(kt+1)
    {
      const char* sA = (const char*)(cur);
      const char* sB = (const char*)(cur + 2 * 8192);
      bf16x8 af[4];
#pragma unroll
      for (int i = 0; i < 4; ++i)
        af[i] = *(const bf16x8*)(sA + ((wm * 128 + i * 16 + l15) << 6) + kbs);
#pragma unroll
      for (int i = 0; i < 4; ++i)
        bfr[i] = *(const bf16x8*)(sB + ((wn * 64 + i * 16 + l15) << 6) + kbs);
      if (p1) STAGE(aR0, aR1, (kt + 1) * 64 + 32, nxt + 1 * 8192);
      BAR();
      __builtin_amdgcn_s_setprio(1);
#pragma unroll
      for (int i = 0; i < 4; ++i)
#pragma unroll
        for (int j = 0; j < 4; ++j)
          acc[i][j] = __builtin_amdgcn_mfma_f32_16x16x32_bf16(af[i], bfr[j], acc[i][j], 0, 0, 0);
      __builtin_amdgcn_s_setprio(0);
      BAR();
    }
    // ---- phase 2: khalf0, mhalf1; stage B1(kt+1); mid-gate
    {
      const char* sA = (const char*)(cur);
      bf16x8 af[4];
#pragma unroll
      for (int i = 0; i < 4; ++i)
        af[i] = *(const bf16x8*)(sA + ((wm * 128 + (4 + i) * 16 + l15) << 6) + kbs);
      if (p1) STAGE(bR0, bR1, (kt + 1) * 64 + 32, nxt + 3 * 8192);
      BAR();
      __builtin_amdgcn_s_setprio(1);
#pragma unroll
      for (int i = 0; i < 4; ++i)
#pragma unroll
        for (int j = 0; j < 4; ++j)
          acc[4 + i][j] = __builtin_amdgcn_mfma_f32_16x16x32_bf16(af[i], bfr[j], acc[4 + i][j], 0, 0, 0);
      __builtin_amdgcn_s_setprio(0);
      if (p1) asm volatile("s_waitcnt vmcnt(8)" ::: "memory");
      else    asm volatile("s_waitcnt vmcnt(0)" ::: "memory");
      BAR();
    }
    // ---- phase 3: khalf1, mhalf0 (+ B khalf1 reads); stage A0(kt+2)
    {
      const char* sA = (const char*)(cur + 1 * 8192);
      const char* sB = (const char*)(cur + 3 * 8192);
      bf16x8 af[4];
#pragma unroll
      for (int i = 0; i < 4; ++i)
        af[i] = *(const bf16x8*)(sA + ((wm * 128 + i * 16 + l15) << 6) + kbs);
#pragma unroll
      for (int i = 0; i < 4; ++i)
        bfr[i] = *(const bf16x8*)(sB + ((wn * 64 + i * 16 + l15) << 6) + kbs);
      if (p2) STAGE(aR0, aR1, (kt + 2) * 64, cur + 0 * 8192);
      BAR();
      __builtin_amdgcn_s_setprio(1);
#pragma unroll
      for (int i = 0; i < 4; ++i)
#pragma unroll
        for (int j = 0; j < 4; ++j)
          acc[i][j] = __builtin_amdgcn_mfma_f32_16x16x32_bf16(af[i], bfr[j], acc[i][j], 0, 0, 0);
      __builtin_amdgcn_s_setprio(0);
      BAR();
    }
    // ---- phase 4: khalf1, mhalf1; stage B0(kt+2); end-gate
    {
      const char* sA = (const char*)(cur + 1 * 8192);
      bf16x8 af[4];
#pragma unroll
      for (int i = 0; i < 4; ++i)
        af[i] = *(const bf16x8*)(sA + ((wm * 128 + (4 + i) * 16 + l15) << 6) + kbs);
      if (p2) STAGE(bR0, bR1, (kt + 2) * 64, cur + 2 * 8192);
      BAR();
      __builtin_amdgcn_s_setprio(1);
#pragma unroll
      for (int i = 0; i < 4; ++i)
#pragma unroll
        for (int j = 0; j < 4; ++j)
          acc[4 + i][j] = __builtin_amdgcn_mfma_f32_16x16x32_bf16(af[i], bfr[j], acc[4 + i][j], 0, 0, 0);
      __builtin_amdgcn_s_setprio(0);
      if (p1) {
        if (p2) asm volatile("s_waitcnt vmcnt(8)" ::: "memory");
        else    asm volatile("s_waitcnt vmcnt(4)" ::: "memory");
      }
      BAR();
    }
  }

  // epilogue: D frag col = lane&15, row = (lane>>4)*4 + j
  const int r0 = bm * 256 + wm * 128 + ((lane >> 4) * 4);
  const int c0 = bn * 256 + wn * 64 + l15;
#pragma unroll
  for (int ni = 0; ni < 4; ++ni) {
    const int col = c0 + ni * 16;
    const float bv = (col < Nbias) ? bias[col] : 0.f;
    const bool cok = (col < Nstore);
#pragma unroll
    for (int mi = 0; mi < 8; ++mi) {
#pragma unroll
      for (int j = 0; j < 4; ++j) {
        float v = acc[mi][ni][j] + bv;
        if (ACT == ACT_RELU) v = fmaxf(v, 0.f);
        else                 v = fminf(fmaxf(v + 1.f, 0.05f), 1e9f);
        if (cok) Cb[(size_t)(r0 + mi * 16 + j) * ldc + col] = (bf16_t)v;
      }
    }
  }
}

// ---------------------------------------------------------------- G5+combine fused:
// Block (bn in 0..3, bm in 0..63): both branches' 128x128 logit tiles (B staged once),
// then 2-way softmax + att-weighted E sums in the epilogue.
__global__ __launch_bounds__(256)
void g5_combine(const bf16_t* __restrict__ H, const bf16_t* __restrict__ Wb,
                const float* __restrict__ ib2, const bf16_t* __restrict__ E,
                float* __restrict__ out) {
  __shared__ __align__(16) bf16_t As1[128 * 64];
  __shared__ __align__(16) bf16_t As2[128 * 64];
  __shared__ __align__(16) bf16_t Bs[128 * 64];

  const int bn = blockIdx.x, bm = blockIdx.y;
  const int t = threadIdx.x;
  const int lane = t & 63;
  const int wv = t >> 6;
  const int wm = wv >> 1, wn = wv & 1;

  f32x4 acc1[4][4], acc2[4][4];
#pragma unroll
  for (int i = 0; i < 4; ++i)
#pragma unroll
    for (int j = 0; j < 4; ++j) { acc1[i][j] = f32x4{0.f,0.f,0.f,0.f}; acc2[i][j] = f32x4{0.f,0.f,0.f,0.f}; }

  const size_t a1Base = (size_t)(bm * 128) * LDA5;
  const size_t a2Base = (size_t)(8192 + bm * 128) * LDA5;
  const size_t bBase  = (size_t)(bn * 128) * LDA5;

  for (int kt = 0; kt < KL5; kt += 64) {
    __syncthreads();
#pragma unroll
    for (int q = 0; q < 4; ++q) {
      const int lin = q * 256 + t;
      const int row = lin >> 3;
      const int kc = ((lin & 7) ^ (row & 7)) * 8;          // swizzled source chunk
      const int lofs = (q * 256 + wv * 64) * 16;
      gload_lds16(H + a1Base + (size_t)row * LDA5 + kt + kc, (char*)As1 + lofs);
      gload_lds16(H + a2Base + (size_t)row * LDA5 + kt + kc, (char*)As2 + lofs);
      gload_lds16(Wb + bBase + (size_t)row * LDA5 + kt + kc, (char*)Bs + lofs);
    }
    __syncthreads();

#pragma unroll
    for (int s = 0; s < 2; ++s) {
      const int crd = s * 4 + (lane >> 4);
      const int k0 = (crd ^ (lane & 7)) * 8;               // swizzled read chunk
      bf16x8 af1[4], af2[4], bf[4];
#pragma unroll
      for (int i = 0; i < 4; ++i) {
        const int ra = wm * 64 + i * 16 + (lane & 15);
        af1[i] = *(const bf16x8*)(As1 + ra * 64 + k0);
        af2[i] = *(const bf16x8*)(As2 + ra * 64 + k0);
        const int rb = wn * 64 + i * 16 + (lane & 15);
        bf[i] = *(const bf16x8*)(Bs + rb * 64 + k0);
      }
#pragma unroll
      for (int mi = 0; mi < 4; ++mi)
#pragma unroll
        for (int ni = 0; ni < 4; ++ni) {
          acc1[mi][ni] = __builtin_amdgcn_mfma_f32_16x16x32_bf16(af1[mi], bf[ni], acc1[mi][ni], 0, 0, 0);
          acc2[mi][ni] = __builtin_amdgcn_mfma_f32_16x16x32_bf16(af2[mi], bf[ni], acc2[mi][ni], 0, 0, 0);
        }
    }
  }

  // epilogue: softmax over 2 branches + weighted E sums
  const int rloc0 = wm * 64 + ((lane >> 4) * 4);
  const int cloc0 = wn * 64 + (lane & 15);
#pragma unroll
  for (int ni = 0; ni < 4; ++ni) {
    const int d = bn * 128 + cloc0 + ni * 16;
    if (d >= 400) continue;
    const float bv = ib2[d];
#pragma unroll
    for (int mi = 0; mi < 4; ++mi) {
#pragma unroll
      for (int j = 0; j < 4; ++j) {
        const int b = bm * 128 + rloc0 + mi * 16 + j;
        const float l1 = acc1[mi][ni][j] + bv;
        const float l2 = acc2[mi][ni][j] + bv;
        const float att1 = 1.f / (1.f + expf(l2 - l1));
        const float att2 = 1.f - att1;
        const bf16_t* E1 = E + (size_t)b * LDC3;
        const bf16_t* E2 = E + (size_t)(8192 + b) * LDC3;
        out[(size_t)b * 400 + d] =
            att1 * (float)E1[d] + att2 * (float)E2[d];
        out[(size_t)8192 * 400 + (size_t)b * 400 + d] =
            att1 * (float)E1[400 + d] + att2 * (float)E2[400 + d];
      }
    }
  }
}

// ----------------------------------------------------------------
extern "C" void kernel_launch(void* const* d_in, const int* in_sizes, int n_in,
                              void* d_out, int out_size, void* d_ws, size_t ws_size,
                              hipStream_t stream) {
  const int* a1 = (const int*)d_in[0];
  const int* r1 = (const int*)d_in[1];
  const int* a2 = (const int*)d_in[2];
  const int* r2 = (const int*)d_in[3];
  const float* ent = (const float*)d_in[4];
  const float* rel = (const float*)d_in[5];
  const float* pW1 = (const float*)d_in[6];
  const float* pb1 = (const float*)d_in[7];
  const float* pW2 = (const float*)d_in[8];
  const float* pb2 = (const float*)d_in[9];
  const float* pW0 = (const float*)d_in[10];
  const float* pb0 = (const float*)d_in[11];
  const float* iW1 = (const float*)d_in[12];
  const float* ib1 = (const float*)d_in[13];
  const float* iW2 = (const float*)d_in[14];
  const float* ib2 = (const float*)d_in[15];

  char* ws = (char*)d_ws;
  size_t o = 0;
  auto take = [&](size_t bytes) { char* p = ws + o; o += (bytes + 255) & ~(size_t)255; return p; };
  bf16_t* W1b  = (bf16_t*)take((size_t)N1c * K1 * 2);
  bf16_t* W2b  = (bf16_t*)take((size_t)N2c * LDA2 * 2);
  bf16_t* W0b  = (bf16_t*)take((size_t)N3c * LDA3 * 2);
  bf16_t* iW1b = (bf16_t*)take((size_t)N4c * LDA4 * 2);
  bf16_t* iW2b = (bf16_t*)take((size_t)N5 * LDA5 * 2);
  char* bufX = take((size_t)M * K1 * 2);   // X bf16 [M,1216]; later E bf16 [M,1024]
  char* bufY = take((size_t)M * LDC1 * 2); // Y bf16 [M,1664]; later H bf16 [M,1024]
  char* bufZ = take((size_t)M * LDC2 * 2); // Z bf16 [M,1664]

  bf16_t* Xb = (bf16_t*)bufX;
  bf16_t* Yb = (bf16_t*)bufY;
  bf16_t* Zb = (bf16_t*)bufZ;
  bf16_t* Eb = (bf16_t*)bufX;   // reuse: X dead after G1
  bf16_t* Hb = (bf16_t*)bufY;   // reuse: Y dead after G2

  // prep: gather (blocks 0..M-1) + all weight converts (rest)
  prep_kernel<<<dim3(PREP_BLOCKS), 256, 0, stream>>>(a1, r1, a2, r2, ent, rel, Xb,
                                                     pW1, pW2, pW0, iW1, iW2,
                                                     W1b, W2b, W0b, iW1b, iW2b);

  // G1: Y = relu(X W1^T + b1)   [16384 x 1792] k=1216
  gemm256<ACT_RELU><<<dim3((N1c / 256) * (M / 256)), 512, 0, stream>>>(
      Xb, W1b, pb1, 1600, Yb, K1, NS1, LDC1, K1 / 64, N1c / 256);
  // G2: Z = relu(Y W2^T + b2)   [16384 x 1792] lda=1664, kloop=1600
  gemm256<ACT_RELU><<<dim3((N2c / 256) * (M / 256)), 512, 0, stream>>>(
      Yb, W2b, pb2, 1600, Zb, LDA2, NS2, LDC2, KL2 / 64, N2c / 256);
  // G3: E = reg(Z W0^T + b0)    [16384 x 1024] lda=1664, kloop=1600 -> bf16 only
  gemm256<ACT_REG><<<dim3((N3c / 256) * (M / 256)), 512, 0, stream>>>(
      Zb, W0b, pb0, 800, Eb, LDA3, NS3, LDC3, KL3 / 64, N3c / 256);
  // G4: H = relu(E iW1^T + ib1) [16384 x 1024] lda=1024, kloop=832
  gemm256<ACT_RELU><<<dim3((N4c / 256) * (M / 256)), 512, 0, stream>>>(
      Eb, iW1b, ib1, 800, Hb, LDA4, NS4, LDC4, KL4 / 64, N4c / 256);
  // G5 + softmax + combine, fused
  g5_combine<<<dim3(N5 / 128, BATCH / 128), 256, 0, stream>>>(
      Hb, iW2b, ib2, Eb, (float*)d_out);
}